// Round 2
// baseline (1197.380 us; speedup 1.0000x reference)
//
#include <hip/hip_runtime.h>

#define KL  2304   // 48*48
#define KC  64
#define KHS 48
#define KHH 96

// ---------------- K0: downsample f,b; per-pixel |bd|^2; downsampled mask ----
__global__ __launch_bounds__(64) void k_prep(const float* __restrict__ f,
    const float* __restrict__ bsrc, const float* __restrict__ mask,
    float* __restrict__ fd, float* __restrict__ bd,
    float* __restrict__ nbuf, float* __restrict__ mdd)
{
    int blk = blockIdx.x;              // nb*KL blocks
    int p = blk % KL, bi = blk / KL;
    int y = p / KHS, x = p % KHS;
    int fy = 2*y + 1, fx = 2*x + 1;
    int c = threadIdx.x;
    size_t src = (((size_t)bi*KHH + fy)*KHH + fx)*KC + c;
    float fv = f[src], bv = bsrc[src];
    size_t dst = ((size_t)bi*KL + p)*KC + c;
    fd[dst] = fv;
    bd[dst] = bv;
    float s = bv*bv;
    #pragma unroll
    for (int off = 32; off > 0; off >>= 1) s += __shfl_down(s, off);
    if (c == 0) {
        nbuf[bi*KL + p] = s;
        mdd[bi*KL + p]  = mask[((size_t)bi*KHH + fy)*KHH + fx];
    }
}

// ---------------- K1: norm[q] = max(sqrt(9-tap sum nb),1e-4); mm from mask --
__global__ __launch_bounds__(256) void k_normmask(const float* __restrict__ nbuf,
    const float* __restrict__ mdd, float* __restrict__ nrm, float* __restrict__ mm)
{
    int i = blockIdx.x*256 + threadIdx.x;   // nb*KL
    int q = i % KL, bi = i / KL;
    int v = q / KHS, u = q % KHS;
    float sn = 0.f, sm = 0.f;
    for (int dy = -1; dy <= 1; dy++) {
        int vv = v + dy; if ((unsigned)vv >= KHS) continue;
        for (int dx = -1; dx <= 1; dx++) {
            int uu = u + dx; if ((unsigned)uu >= KHS) continue;
            sn += nbuf[bi*KL + vv*KHS + uu];
            sm += mdd[bi*KL + vv*KHS + uu];
        }
    }
    nrm[i] = fmaxf(sqrtf(sn), 1e-4f);
    mm[i]  = (sm == 0.0f) ? 1.0f : 0.0f;   // mean over 9 == 0 <=> sum == 0
}

// ---------------- K2: D = fd * bd^T  (M=N=2304, K=64), batched -------------
__global__ __launch_bounds__(256) void k_gemmD(const float* __restrict__ fd,
    const float* __restrict__ bd, float* __restrict__ D)
{
    int bi = blockIdx.z;
    int m0 = blockIdx.y*64, n0 = blockIdx.x*64;
    const float* A = fd + (size_t)bi*KL*KC;   // [m][k]
    const float* B = bd + (size_t)bi*KL*KC;   // [n][k]
    __shared__ float As[64][65];  // [k][m]
    __shared__ float Bs[64][65];  // [k][n]
    int t = threadIdx.x;
    #pragma unroll
    for (int i = 0; i < 16; i++) {
        int idx = t + i*256; int r = idx >> 6, c = idx & 63;
        As[c][r] = A[(size_t)(m0 + r)*KC + c];
        Bs[c][r] = B[(size_t)(n0 + r)*KC + c];
    }
    __syncthreads();
    int tx = t & 15, ty = t >> 4;
    float acc[4][4] = {};
    #pragma unroll 8
    for (int k = 0; k < 64; k++) {
        float a[4], bb[4];
        #pragma unroll
        for (int i = 0; i < 4; i++) a[i]  = As[k][ty*4 + i];
        #pragma unroll
        for (int j = 0; j < 4; j++) bb[j] = Bs[k][tx*4 + j];
        #pragma unroll
        for (int i = 0; i < 4; i++)
            #pragma unroll
            for (int j = 0; j < 4; j++) acc[i][j] += a[i]*bb[j];
    }
    for (int i = 0; i < 4; i++) {
        int m = m0 + ty*4 + i;
        for (int j = 0; j < 4; j++)
            D[((size_t)bi*KL + m)*KL + n0 + tx*4 + j] = acc[i][j];
    }
}

// ---------------- K3: S[p,q] = (sum_diag D[p+d,q+d]) / nrm[q] ---------------
__global__ __launch_bounds__(256) void k_diagnorm(const float* __restrict__ D,
    const float* __restrict__ nrm, float* __restrict__ S)
{
    int q = blockIdx.x*256 + threadIdx.x;
    int p = blockIdx.y, bi = blockIdx.z;
    int y = p / KHS, x = p % KHS, v = q / KHS, u = q % KHS;
    const float* Db = D + (size_t)bi*KL*KL;
    float acc = 0.f;
    for (int dy = -1; dy <= 1; dy++) {
        int yy = y + dy, vv = v + dy;
        if ((unsigned)yy >= KHS || (unsigned)vv >= KHS) continue;
        for (int dx = -1; dx <= 1; dx++) {
            int xx = x + dx, uu = u + dx;
            if ((unsigned)xx >= KHS || (unsigned)uu >= KHS) continue;
            acc += Db[(size_t)(yy*KHS + xx)*KL + vv*KHS + uu];
        }
    }
    S[((size_t)bi*KL + p)*KL + q] = acc / nrm[bi*KL + q];
}

// ---------------- K4: fuse conv #1 over flat (p,q) --------------------------
__global__ __launch_bounds__(256) void k_fuse1(const float* __restrict__ S,
    const float* __restrict__ fw, float* __restrict__ Y1)
{
    int q = blockIdx.x*256 + threadIdx.x;
    int p = blockIdx.y, bi = blockIdx.z;
    const float* Sb = S + (size_t)bi*KL*KL;
    float w[9];
    #pragma unroll
    for (int i = 0; i < 9; i++) w[i] = fw[i];
    float acc = 0.f;
    #pragma unroll
    for (int a = 0; a < 3; a++) {
        int pp = p + a - 1; if ((unsigned)pp >= KL) continue;
        #pragma unroll
        for (int b = 0; b < 3; b++) {
            int qq = q + b - 1; if ((unsigned)qq >= KL) continue;
            acc += w[a*3 + b] * Sb[(size_t)pp*KL + qq];
        }
    }
    Y1[((size_t)bi*KL + p)*KL + q] = acc;
}

// ---------------- K5: fuse conv #2 on transposed flat indices ---------------
__global__ __launch_bounds__(256) void k_fuse2(const float* __restrict__ Y1,
    const float* __restrict__ fw, float* __restrict__ Y2)
{
    int q = blockIdx.x*256 + threadIdx.x;
    int p = blockIdx.y, bi = blockIdx.z;
    int y = p / KHS, x = p % KHS, v = q / KHS, u = q % KHS;
    const float* Yb = Y1 + (size_t)bi*KL*KL;
    float w[9];
    #pragma unroll
    for (int i = 0; i < 9; i++) w[i] = fw[i];
    int tp = x*KHS + y, tq = u*KHS + v;
    float acc = 0.f;
    #pragma unroll
    for (int a = 0; a < 3; a++) {
        int t2 = tp + a - 1; if ((unsigned)t2 >= KL) continue;
        int pr = (t2 % KHS)*KHS + (t2 / KHS);
        #pragma unroll
        for (int b = 0; b < 3; b++) {
            int s2 = tq + b - 1; if ((unsigned)s2 >= KL) continue;
            int qr = (s2 % KHS)*KHS + (s2 / KHS);
            acc += w[a*3 + b] * Yb[(size_t)pr*KL + qr];
        }
    }
    Y2[((size_t)bi*KL + p)*KL + q] = acc;
}

// ---------------- K6: masked scaled row softmax (in place) ------------------
__global__ __launch_bounds__(256) void k_softmax(float* __restrict__ Y,
    const float* __restrict__ mm)
{
    int p = blockIdx.x, bi = blockIdx.y;
    float* row = Y + ((size_t)bi*KL + p)*KL;
    const float* mmb = mm + bi*KL;
    __shared__ float red[16];
    int t = threadIdx.x;
    float vals[9];
    float lmax = -1e30f;
    #pragma unroll
    for (int i = 0; i < 9; i++) {
        int q = t + i*256;
        float v = row[q]*mmb[q]*10.0f;
        vals[i] = v;
        lmax = fmaxf(lmax, v);
    }
    #pragma unroll
    for (int off = 32; off > 0; off >>= 1) lmax = fmaxf(lmax, __shfl_down(lmax, off));
    if ((t & 63) == 0) red[t >> 6] = lmax;
    __syncthreads();
    if (t == 0) {
        float m = red[0];
        for (int i = 1; i < 4; i++) m = fmaxf(m, red[i]);
        red[0] = m;
    }
    __syncthreads();
    float bmax = red[0];
    float lsum = 0.f;
    #pragma unroll
    for (int i = 0; i < 9; i++) {
        float e = __expf(vals[i] - bmax);
        vals[i] = e;
        lsum += e;
    }
    #pragma unroll
    for (int off = 32; off > 0; off >>= 1) lsum += __shfl_down(lsum, off);
    if ((t & 63) == 0) red[8 + (t >> 6)] = lsum;
    __syncthreads();
    if (t == 0) {
        float s = red[8];
        for (int i = 1; i < 4; i++) s += red[8 + i];
        red[8] = s;
    }
    __syncthreads();
    float inv = 1.0f / red[8];
    #pragma unroll
    for (int i = 0; i < 9; i++) {
        int q = t + i*256;
        row[q] = vals[i]*inv*mmb[q];
    }
}

// ---------------- KR: materialize R[q, (ky,kx,c)] from b --------------------
// one thread per element of R: nb*KL*16*64 elements total
__global__ __launch_bounds__(256) void k_buildR(const float* __restrict__ bsrc,
    float* __restrict__ R)
{
    size_t gid = (size_t)blockIdx.x*256 + threadIdx.x;   // nb*KL*16*64 threads
    int c = gid & 63;
    size_t t1 = gid >> 6;
    int jj = t1 & 15;
    size_t t2 = t1 >> 4;
    int q  = (int)(t2 % KL);
    int bi = (int)(t2 / KL);
    int v = q / KHS, u = q % KHS;
    int ky = jj >> 2, kx = jj & 3;
    int ry = 2*v + ky - 1, rx = 2*u + kx - 1;
    float val = 0.f;
    if ((unsigned)ry < KHH && (unsigned)rx < KHH)
        val = bsrc[(((size_t)bi*KHH + ry)*KHH + rx)*KC + c];
    R[gid] = val;
}

// ---------------- K7: P = Y * R  (M=2304, N=1024, K=2304), batched ----------
__global__ __launch_bounds__(256) void k_gemmP(const float* __restrict__ Y,
    const float* __restrict__ R, float* __restrict__ P)
{
    int bi = blockIdx.z;
    int m0 = blockIdx.y*64, n0 = blockIdx.x*64;
    const float* Yb = Y + (size_t)bi*KL*KL;
    const float* Rb = R + (size_t)bi*KL*1024;
    __shared__ float As[16][65];   // [k][m]
    __shared__ float Bs[16][64];   // [k][n]
    int t = threadIdx.x;
    int tx = t & 15, ty = t >> 4;
    float acc[4][4] = {};
    for (int k0 = 0; k0 < KL; k0 += 16) {
        #pragma unroll
        for (int i = 0; i < 4; i++) {
            int idx = t + i*256; int r = idx >> 4, kk = idx & 15;
            As[kk][r] = Yb[(size_t)(m0 + r)*KL + k0 + kk];
        }
        #pragma unroll
        for (int i = 0; i < 4; i++) {
            int idx = t + i*256; int r = idx >> 6, c2 = idx & 63;
            Bs[r][c2] = Rb[(size_t)(k0 + r)*1024 + n0 + c2];
        }
        __syncthreads();
        #pragma unroll
        for (int kk = 0; kk < 16; kk++) {
            float a[4], bb[4];
            #pragma unroll
            for (int i = 0; i < 4; i++) a[i]  = As[kk][ty*4 + i];
            #pragma unroll
            for (int j = 0; j < 4; j++) bb[j] = Bs[kk][tx*4 + j];
            #pragma unroll
            for (int i = 0; i < 4; i++)
                #pragma unroll
                for (int j = 0; j < 4; j++) acc[i][j] += a[i]*bb[j];
        }
        __syncthreads();
    }
    for (int i = 0; i < 4; i++) {
        int m = m0 + ty*4 + i;
        for (int j = 0; j < 4; j++)
            P[((size_t)bi*KL + m)*1024 + n0 + tx*4 + j] = acc[i][j];
    }
}

// ---------------- K8: overlap-add (adjoint of stride-2 4x4 SAME conv), /4 ---
__global__ __launch_bounds__(256) void k_overlap(const float* __restrict__ P,
    float* __restrict__ out)
{
    size_t gid = (size_t)blockIdx.x*256 + threadIdx.x;   // nb*96*96*64
    int c = gid & 63;
    size_t r = gid >> 6;
    int ix = (int)(r % KHH); r /= KHH;
    int iy = (int)(r % KHH);
    int bi = (int)(r / KHH);
    float acc = 0.f;
    #pragma unroll
    for (int sy = 0; sy < 2; sy++) {
        int ky = (iy & 1) ? (sy*2) : (sy*2 + 1);
        int yp = (iy + 1 - ky) >> 1;
        if ((unsigned)yp >= KHS) continue;
        #pragma unroll
        for (int sx = 0; sx < 2; sx++) {
            int kx = (ix & 1) ? (sx*2) : (sx*2 + 1);
            int xp = (ix + 1 - kx) >> 1;
            if ((unsigned)xp >= KHS) continue;
            acc += P[(((size_t)bi*KL + yp*KHS + xp)*16 + (ky*4 + kx))*64 + c];
        }
    }
    out[gid] = 0.25f * acc;
}

extern "C" void kernel_launch(void* const* d_in, const int* in_sizes, int n_in,
                              void* d_out, int out_size, void* d_ws, size_t ws_size,
                              hipStream_t stream)
{
    const float* f    = (const float*)d_in[0];
    const float* b    = (const float*)d_in[1];
    const float* mask = (const float*)d_in[2];
    const float* fw   = (const float*)d_in[3];
    float* out = (float*)d_out;

    // workspace need per chunk of nbc samples (floats):
    //   2*KL*KC (fd,bd) + 4*KL (nb,mdd,nrm,mm) + 2*KL*KL (bufA,bufB)
    auto need = [](int nbc) -> size_t {
        return (size_t)nbc * (2ull*KL*KC + 4ull*KL + 2ull*(size_t)KL*KL) * 4ull;
    };
    int nbc = 4;
    if (need(nbc) > ws_size) nbc = 2;
    if (need(nbc) > ws_size) nbc = 1;

    for (int bi0 = 0; bi0 < 4; bi0 += nbc) {
        int nb = (4 - bi0 < nbc) ? (4 - bi0) : nbc;
        const float* fc = f    + (size_t)bi0*KHH*KHH*KC;
        const float* bc = b    + (size_t)bi0*KHH*KHH*KC;
        const float* mc = mask + (size_t)bi0*KHH*KHH;
        float* outc = out + (size_t)bi0*KHH*KHH*KC;

        float* w    = (float*)d_ws;
        float* fd   = w;  w += (size_t)nbc*KL*KC;
        float* bd   = w;  w += (size_t)nbc*KL*KC;
        float* nbuf = w;  w += (size_t)nbc*KL;
        float* mdd  = w;  w += (size_t)nbc*KL;
        float* nrm  = w;  w += (size_t)nbc*KL;
        float* mmb  = w;  w += (size_t)nbc*KL;
        float* bufA = w;  w += (size_t)nbc*KL*KL;
        float* bufB = w;
        float* Pbuf = bufA;                              // after Y1 consumed
        float* Rbuf = bufA + (size_t)nbc*KL*1024;        // disjoint from Pbuf

        k_prep    <<<nb*KL, 64, 0, stream>>>(fc, bc, mc, fd, bd, nbuf, mdd);
        k_normmask<<<(nb*KL)/256, 256, 0, stream>>>(nbuf, mdd, nrm, mmb);
        k_gemmD   <<<dim3(36, 36, nb), 256, 0, stream>>>(fd, bd, bufA);
        k_diagnorm<<<dim3(9, KL, nb), 256, 0, stream>>>(bufA, nrm, bufB);
        k_fuse1   <<<dim3(9, KL, nb), 256, 0, stream>>>(bufB, fw, bufA);
        k_fuse2   <<<dim3(9, KL, nb), 256, 0, stream>>>(bufA, fw, bufB);
        k_buildR  <<<(nb*KL*1024)/256, 256, 0, stream>>>(bc, Rbuf);
        k_softmax <<<dim3(KL, nb), 256, 0, stream>>>(bufB, mmb);
        k_gemmP   <<<dim3(16, 36, nb), 256, 0, stream>>>(bufB, Rbuf, Pbuf);
        k_overlap <<<nb*KL, 256, 0, stream>>>(Pbuf, outc);
    }
}

// Round 3
// 674.356 us; speedup vs baseline: 1.7756x; 1.7756x over previous
//
#include <hip/hip_runtime.h>
#include <hip/hip_bf16.h>

#define KL  2304   // 48*48
#define KC  64
#define KHS 48
#define KHH 96

typedef __attribute__((ext_vector_type(8))) short bf16x8;
typedef __attribute__((ext_vector_type(4))) float f32x4;

static __device__ inline unsigned short f2bf(float x) {
    __hip_bfloat16 h = __float2bfloat16(x);
    return *reinterpret_cast<unsigned short*>(&h);
}

// ---------------- K0: downsample f,b; per-pixel |bd|^2; downsampled mask ----
__global__ __launch_bounds__(64) void k_prep(const float* __restrict__ f,
    const float* __restrict__ bsrc, const float* __restrict__ mask,
    float* __restrict__ fd, float* __restrict__ bd,
    float* __restrict__ nbuf, float* __restrict__ mdd)
{
    int blk = blockIdx.x;              // nb*KL blocks
    int p = blk % KL, bi = blk / KL;
    int y = p / KHS, x = p % KHS;
    int fy = 2*y + 1, fx = 2*x + 1;
    int c = threadIdx.x;
    size_t src = (((size_t)bi*KHH + fy)*KHH + fx)*KC + c;
    float fv = f[src], bv = bsrc[src];
    size_t dst = ((size_t)bi*KL + p)*KC + c;
    fd[dst] = fv;
    bd[dst] = bv;
    float s = bv*bv;
    #pragma unroll
    for (int off = 32; off > 0; off >>= 1) s += __shfl_down(s, off);
    if (c == 0) {
        nbuf[bi*KL + p] = s;
        mdd[bi*KL + p]  = mask[((size_t)bi*KHH + fy)*KHH + fx];
    }
}

// ---------------- K1: norm[q] = max(sqrt(9-tap sum nb),1e-4); mm from mask --
__global__ __launch_bounds__(256) void k_normmask(const float* __restrict__ nbuf,
    const float* __restrict__ mdd, float* __restrict__ nrm, float* __restrict__ mm)
{
    int i = blockIdx.x*256 + threadIdx.x;   // nb*KL
    int q = i % KL, bi = i / KL;
    int v = q / KHS, u = q % KHS;
    float sn = 0.f, sm = 0.f;
    for (int dy = -1; dy <= 1; dy++) {
        int vv = v + dy; if ((unsigned)vv >= KHS) continue;
        for (int dx = -1; dx <= 1; dx++) {
            int uu = u + dx; if ((unsigned)uu >= KHS) continue;
            sn += nbuf[bi*KL + vv*KHS + uu];
            sm += mdd[bi*KL + vv*KHS + uu];
        }
    }
    nrm[i] = fmaxf(sqrtf(sn), 1e-4f);
    mm[i]  = (sm == 0.0f) ? 1.0f : 0.0f;   // mean over 9 == 0 <=> sum == 0
}

// ---------------- K2: D = fd * bd^T  (M=N=2304, K=64), batched (fp32) ------
__global__ __launch_bounds__(256) void k_gemmD(const float* __restrict__ fd,
    const float* __restrict__ bd, float* __restrict__ D)
{
    int bi = blockIdx.z;
    int m0 = blockIdx.y*64, n0 = blockIdx.x*64;
    const float* A = fd + (size_t)bi*KL*KC;   // [m][k]
    const float* B = bd + (size_t)bi*KL*KC;   // [n][k]
    __shared__ float As[64][65];  // [k][m]
    __shared__ float Bs[64][65];  // [k][n]
    int t = threadIdx.x;
    #pragma unroll
    for (int i = 0; i < 16; i++) {
        int idx = t + i*256; int r = idx >> 6, c = idx & 63;
        As[c][r] = A[(size_t)(m0 + r)*KC + c];
        Bs[c][r] = B[(size_t)(n0 + r)*KC + c];
    }
    __syncthreads();
    int tx = t & 15, ty = t >> 4;
    float acc[4][4] = {};
    #pragma unroll 8
    for (int k = 0; k < 64; k++) {
        float a[4], bb[4];
        #pragma unroll
        for (int i = 0; i < 4; i++) a[i]  = As[k][ty*4 + i];
        #pragma unroll
        for (int j = 0; j < 4; j++) bb[j] = Bs[k][tx*4 + j];
        #pragma unroll
        for (int i = 0; i < 4; i++)
            #pragma unroll
            for (int j = 0; j < 4; j++) acc[i][j] += a[i]*bb[j];
    }
    for (int i = 0; i < 4; i++) {
        int m = m0 + ty*4 + i;
        for (int j = 0; j < 4; j++)
            D[((size_t)bi*KL + m)*KL + n0 + tx*4 + j] = acc[i][j];
    }
}

// ---------------- K3: S[p,q] = (sum_diag D[p+d,q+d]) / nrm[q] ---------------
__global__ __launch_bounds__(256) void k_diagnorm(const float* __restrict__ D,
    const float* __restrict__ nrm, float* __restrict__ S)
{
    int q = blockIdx.x*256 + threadIdx.x;
    int p = blockIdx.y, bi = blockIdx.z;
    int y = p / KHS, x = p % KHS, v = q / KHS, u = q % KHS;
    const float* Db = D + (size_t)bi*KL*KL;
    float acc = 0.f;
    for (int dy = -1; dy <= 1; dy++) {
        int yy = y + dy, vv = v + dy;
        if ((unsigned)yy >= KHS || (unsigned)vv >= KHS) continue;
        for (int dx = -1; dx <= 1; dx++) {
            int xx = x + dx, uu = u + dx;
            if ((unsigned)xx >= KHS || (unsigned)uu >= KHS) continue;
            acc += Db[(size_t)(yy*KHS + xx)*KL + vv*KHS + uu];
        }
    }
    S[((size_t)bi*KL + p)*KL + q] = acc / nrm[bi*KL + q];
}

// ---------------- K4: fuse conv #1 over flat (p,q) --------------------------
__global__ __launch_bounds__(256) void k_fuse1(const float* __restrict__ S,
    const float* __restrict__ fw, float* __restrict__ Y1)
{
    int q = blockIdx.x*256 + threadIdx.x;
    int p = blockIdx.y, bi = blockIdx.z;
    const float* Sb = S + (size_t)bi*KL*KL;
    float w[9];
    #pragma unroll
    for (int i = 0; i < 9; i++) w[i] = fw[i];
    float acc = 0.f;
    #pragma unroll
    for (int a = 0; a < 3; a++) {
        int pp = p + a - 1; if ((unsigned)pp >= KL) continue;
        #pragma unroll
        for (int b = 0; b < 3; b++) {
            int qq = q + b - 1; if ((unsigned)qq >= KL) continue;
            acc += w[a*3 + b] * Sb[(size_t)pp*KL + qq];
        }
    }
    Y1[((size_t)bi*KL + p)*KL + q] = acc;
}

// ---------------- K5: fuse conv #2 on transposed flat indices ---------------
__global__ __launch_bounds__(256) void k_fuse2(const float* __restrict__ Y1,
    const float* __restrict__ fw, float* __restrict__ Y2)
{
    int q = blockIdx.x*256 + threadIdx.x;
    int p = blockIdx.y, bi = blockIdx.z;
    int y = p / KHS, x = p % KHS, v = q / KHS, u = q % KHS;
    const float* Yb = Y1 + (size_t)bi*KL*KL;
    float w[9];
    #pragma unroll
    for (int i = 0; i < 9; i++) w[i] = fw[i];
    int tp = x*KHS + y, tq = u*KHS + v;
    float acc = 0.f;
    #pragma unroll
    for (int a = 0; a < 3; a++) {
        int t2 = tp + a - 1; if ((unsigned)t2 >= KL) continue;
        int pr = (t2 % KHS)*KHS + (t2 / KHS);
        #pragma unroll
        for (int b = 0; b < 3; b++) {
            int s2 = tq + b - 1; if ((unsigned)s2 >= KL) continue;
            int qr = (s2 % KHS)*KHS + (s2 / KHS);
            acc += w[a*3 + b] * Yb[(size_t)pr*KL + qr];
        }
    }
    Y2[((size_t)bi*KL + p)*KL + q] = acc;
}

// ---------------- K6: masked scaled row softmax -> bf16 Y -------------------
__global__ __launch_bounds__(256) void k_softmax(const float* __restrict__ Yin,
    const float* __restrict__ mm, unsigned short* __restrict__ Ybf)
{
    int p = blockIdx.x, bi = blockIdx.y;
    const float* row = Yin + ((size_t)bi*KL + p)*KL;
    unsigned short* orow = Ybf + ((size_t)bi*KL + p)*KL;
    const float* mmb = mm + bi*KL;
    __shared__ float red[16];
    int t = threadIdx.x;
    float vals[9];
    float lmax = -1e30f;
    #pragma unroll
    for (int i = 0; i < 9; i++) {
        int q = t + i*256;
        float v = row[q]*mmb[q]*10.0f;
        vals[i] = v;
        lmax = fmaxf(lmax, v);
    }
    #pragma unroll
    for (int off = 32; off > 0; off >>= 1) lmax = fmaxf(lmax, __shfl_down(lmax, off));
    if ((t & 63) == 0) red[t >> 6] = lmax;
    __syncthreads();
    if (t == 0) {
        float m = red[0];
        for (int i = 1; i < 4; i++) m = fmaxf(m, red[i]);
        red[0] = m;
    }
    __syncthreads();
    float bmax = red[0];
    float lsum = 0.f;
    #pragma unroll
    for (int i = 0; i < 9; i++) {
        float e = __expf(vals[i] - bmax);
        vals[i] = e;
        lsum += e;
    }
    #pragma unroll
    for (int off = 32; off > 0; off >>= 1) lsum += __shfl_down(lsum, off);
    if ((t & 63) == 0) red[8 + (t >> 6)] = lsum;
    __syncthreads();
    if (t == 0) {
        float s = red[8];
        for (int i = 1; i < 4; i++) s += red[8 + i];
        red[8] = s;
    }
    __syncthreads();
    float inv = 1.0f / red[8];
    #pragma unroll
    for (int i = 0; i < 9; i++) {
        int q = t + i*256;
        orow[q] = f2bf(vals[i]*inv*mmb[q]);
    }
}

// ---------------- KR: Rt[n][k] bf16, n=(ky,kx,c), k=q; vectorized over k ----
__global__ __launch_bounds__(256) void k_buildRt(const float* __restrict__ bsrc,
    unsigned short* __restrict__ Rt)
{
    int idx = blockIdx.x*256 + threadIdx.x;   // nb*1024*288
    int k8 = idx % 288;
    int rest = idx / 288;
    int n  = rest % 1024;
    int bi = rest / 1024;
    int jj = n >> 6, c = n & 63;
    int ky = jj >> 2, kx = jj & 3;
    int k0 = k8*8;
    bf16x8 vv;
    #pragma unroll
    for (int j = 0; j < 8; j++) {
        int q = k0 + j;
        int v = q / KHS, u = q % KHS;
        int ry = 2*v + ky - 1, rx = 2*u + kx - 1;
        float val = 0.f;
        if ((unsigned)ry < KHH && (unsigned)rx < KHH)
            val = bsrc[(((size_t)bi*KHH + ry)*KHH + rx)*KC + c];
        vv[j] = (short)f2bf(val);
    }
    *(bf16x8*)&Rt[((size_t)bi*1024 + n)*KL + k0] = vv;
}

// ---------------- K7: P = Y * Rt^T via bf16 MFMA ----------------------------
// Y: [M=2304][K=2304] bf16 row-major; Rt: [N=1024][K=2304] bf16 row-major
// P: [M][N] fp32. Tile 128x128, BK=32, 4 waves x (4x4) 16x16x32 MFMAs.
__global__ __launch_bounds__(256) void k_gemmP_mfma(const unsigned short* __restrict__ Y,
    const unsigned short* __restrict__ Rt, float* __restrict__ P)
{
    int bi = blockIdx.z;
    int m0 = blockIdx.y*128, n0 = blockIdx.x*128;
    const unsigned short* Yb = Y  + (size_t)bi*KL*KL;
    const unsigned short* Rb = Rt + (size_t)bi*1024*KL;
    __shared__ unsigned short As[128*40];   // rows padded to 40 bf16 (80 B)
    __shared__ unsigned short Bs[128*40];
    int t = threadIdx.x;
    int lane = t & 63, w = t >> 6;
    int wm = (w >> 1)*64, wn = (w & 1)*64;
    int l15 = lane & 15, quad = lane >> 4;
    f32x4 acc[4][4];
    #pragma unroll
    for (int i = 0; i < 4; i++)
        #pragma unroll
        for (int j = 0; j < 4; j++) acc[i][j] = (f32x4){0.f,0.f,0.f,0.f};

    for (int k0 = 0; k0 < KL; k0 += 32) {
        #pragma unroll
        for (int i = 0; i < 2; i++) {
            int slot = t + i*256;
            int r = slot >> 2, ch = slot & 3;
            bf16x8 va = *(const bf16x8*)&Yb[(size_t)(m0 + r)*KL + k0 + ch*8];
            *(bf16x8*)&As[r*40 + ch*8] = va;
            bf16x8 vb = *(const bf16x8*)&Rb[(size_t)(n0 + r)*KL + k0 + ch*8];
            *(bf16x8*)&Bs[r*40 + ch*8] = vb;
        }
        __syncthreads();
        bf16x8 af[4], bf[4];
        #pragma unroll
        for (int mi = 0; mi < 4; mi++)
            af[mi] = *(const bf16x8*)&As[(wm + mi*16 + l15)*40 + quad*8];
        #pragma unroll
        for (int ni = 0; ni < 4; ni++)
            bf[ni] = *(const bf16x8*)&Bs[(wn + ni*16 + l15)*40 + quad*8];
        #pragma unroll
        for (int mi = 0; mi < 4; mi++)
            #pragma unroll
            for (int ni = 0; ni < 4; ni++)
                acc[mi][ni] = __builtin_amdgcn_mfma_f32_16x16x32_bf16(
                    af[mi], bf[ni], acc[mi][ni], 0, 0, 0);
        __syncthreads();
    }
    #pragma unroll
    for (int mi = 0; mi < 4; mi++) {
        #pragma unroll
        for (int ni = 0; ni < 4; ni++) {
            int col = n0 + wn + ni*16 + l15;
            #pragma unroll
            for (int r = 0; r < 4; r++) {
                int row = m0 + wm + mi*16 + quad*4 + r;
                P[((size_t)bi*KL + row)*1024 + col] = acc[mi][ni][r];
            }
        }
    }
}

// ---------------- K8: overlap-add (adjoint of stride-2 4x4 SAME conv), /4 ---
__global__ __launch_bounds__(256) void k_overlap(const float* __restrict__ P,
    float* __restrict__ out)
{
    size_t gid = (size_t)blockIdx.x*256 + threadIdx.x;   // nb*96*96*64
    int c = gid & 63;
    size_t r = gid >> 6;
    int ix = (int)(r % KHH); r /= KHH;
    int iy = (int)(r % KHH);
    int bi = (int)(r / KHH);
    float acc = 0.f;
    #pragma unroll
    for (int sy = 0; sy < 2; sy++) {
        int ky = (iy & 1) ? (sy*2) : (sy*2 + 1);
        int yp = (iy + 1 - ky) >> 1;
        if ((unsigned)yp >= KHS) continue;
        #pragma unroll
        for (int sx = 0; sx < 2; sx++) {
            int kx = (ix & 1) ? (sx*2) : (sx*2 + 1);
            int xp = (ix + 1 - kx) >> 1;
            if ((unsigned)xp >= KHS) continue;
            acc += P[(((size_t)bi*KL + yp*KHS + xp)*16 + (ky*4 + kx))*64 + c];
        }
    }
    out[gid] = 0.25f * acc;
}

extern "C" void kernel_launch(void* const* d_in, const int* in_sizes, int n_in,
                              void* d_out, int out_size, void* d_ws, size_t ws_size,
                              hipStream_t stream)
{
    const float* f    = (const float*)d_in[0];
    const float* b    = (const float*)d_in[1];
    const float* mask = (const float*)d_in[2];
    const float* fw   = (const float*)d_in[3];
    float* out = (float*)d_out;

    // workspace per chunk of nbc samples (floats):
    //   2*KL*KC (fd,bd) + 4*KL + 2*KL*KL (bufA,bufB)
    auto need = [](int nbc) -> size_t {
        return (size_t)nbc * (2ull*KL*KC + 4ull*KL + 2ull*(size_t)KL*KL) * 4ull;
    };
    int nbc = 4;
    if (need(nbc) > ws_size) nbc = 2;
    if (need(nbc) > ws_size) nbc = 1;

    for (int bi0 = 0; bi0 < 4; bi0 += nbc) {
        int nb = (4 - bi0 < nbc) ? (4 - bi0) : nbc;
        const float* fc = f    + (size_t)bi0*KHH*KHH*KC;
        const float* bc = b    + (size_t)bi0*KHH*KHH*KC;
        const float* mc = mask + (size_t)bi0*KHH*KHH;
        float* outc = out + (size_t)bi0*KHH*KHH*KC;

        float* w    = (float*)d_ws;
        float* fd   = w;  w += (size_t)nbc*KL*KC;
        float* bd   = w;  w += (size_t)nbc*KL*KC;
        float* nbuf = w;  w += (size_t)nbc*KL;
        float* mdd  = w;  w += (size_t)nbc*KL;
        float* nrm  = w;  w += (size_t)nbc*KL;
        float* mmb  = w;  w += (size_t)nbc*KL;
        float* bufA = w;  w += (size_t)nbc*KL*KL;
        float* bufB = w;
        // reuse layout after softmax:
        //   Ybf (bf16)  = bufA[0 .. nbc*KL*KL*2 B)
        //   Pbuf (fp32) = bufA + nbc*KL*KL/2 floats (37.7 MB, fits remaining)
        //   Rt  (bf16)  = bufB (18.9 MB of its 84.9 MB)
        unsigned short* Ybf = (unsigned short*)bufA;
        float* Pbuf = bufA + (size_t)nbc*KL*KL/2;
        unsigned short* Rtb = (unsigned short*)bufB;

        k_prep    <<<nb*KL, 64, 0, stream>>>(fc, bc, mc, fd, bd, nbuf, mdd);
        k_normmask<<<(nb*KL)/256, 256, 0, stream>>>(nbuf, mdd, nrm, mmb);
        k_gemmD   <<<dim3(36, 36, nb), 256, 0, stream>>>(fd, bd, bufA);
        k_diagnorm<<<dim3(9, KL, nb), 256, 0, stream>>>(bufA, nrm, bufB);
        k_fuse1   <<<dim3(9, KL, nb), 256, 0, stream>>>(bufB, fw, bufA);
        k_fuse2   <<<dim3(9, KL, nb), 256, 0, stream>>>(bufA, fw, bufB);
        // softmax reads bufB (fp32 Y2), writes bf16 into bufA (Ybf)
        k_softmax <<<dim3(KL, nb), 256, 0, stream>>>(bufB, mmb, Ybf);
        // bufB now free -> build Rt there
        k_buildRt <<<(nb*1024*288)/256, 256, 0, stream>>>(bc, Rtb);
        k_gemmP_mfma<<<dim3(8, 18, nb), 256, 0, stream>>>(Ybf, Rtb, Pbuf);
        k_overlap <<<nb*KL, 256, 0, stream>>>(Pbuf, outc);
    }
}

// Round 4
// 535.630 us; speedup vs baseline: 2.2355x; 1.2590x over previous
//
#include <hip/hip_runtime.h>
#include <hip/hip_bf16.h>

#define KL  2304   // 48*48
#define KC  64
#define KHS 48
#define KHH 96

typedef __attribute__((ext_vector_type(8))) short bf16x8;
typedef __attribute__((ext_vector_type(4))) float f32x4;

static __device__ inline unsigned short f2bf(float x) {
    __hip_bfloat16 h = __float2bfloat16(x);
    return *reinterpret_cast<unsigned short*>(&h);
}

// ---------------- K0: downsample f,b; per-pixel |bd|^2; downsampled mask ----
__global__ __launch_bounds__(64) void k_prep(const float* __restrict__ f,
    const float* __restrict__ bsrc, const float* __restrict__ mask,
    float* __restrict__ fd, float* __restrict__ bd,
    float* __restrict__ nbuf, float* __restrict__ mdd)
{
    int blk = blockIdx.x;              // nb*KL blocks
    int p = blk % KL, bi = blk / KL;
    int y = p / KHS, x = p % KHS;
    int fy = 2*y + 1, fx = 2*x + 1;
    int c = threadIdx.x;
    size_t src = (((size_t)bi*KHH + fy)*KHH + fx)*KC + c;
    float fv = f[src], bv = bsrc[src];
    size_t dst = ((size_t)bi*KL + p)*KC + c;
    fd[dst] = fv;
    bd[dst] = bv;
    float s = bv*bv;
    #pragma unroll
    for (int off = 32; off > 0; off >>= 1) s += __shfl_down(s, off);
    if (c == 0) {
        nbuf[bi*KL + p] = s;
        mdd[bi*KL + p]  = mask[((size_t)bi*KHH + fy)*KHH + fx];
    }
}

// ------- K1: rnrm[q] = 1/max(sqrt(9-tap sum nb),1e-4); mm from mask --------
__global__ __launch_bounds__(256) void k_normmask(const float* __restrict__ nbuf,
    const float* __restrict__ mdd, float* __restrict__ rnrm, float* __restrict__ mm)
{
    int i = blockIdx.x*256 + threadIdx.x;   // nb*KL
    int q = i % KL, bi = i / KL;
    int v = q / KHS, u = q % KHS;
    float sn = 0.f, sm = 0.f;
    for (int dy = -1; dy <= 1; dy++) {
        int vv = v + dy; if ((unsigned)vv >= KHS) continue;
        for (int dx = -1; dx <= 1; dx++) {
            int uu = u + dx; if ((unsigned)uu >= KHS) continue;
            sn += nbuf[bi*KL + vv*KHS + uu];
            sm += mdd[bi*KL + vv*KHS + uu];
        }
    }
    rnrm[i] = 1.0f / fmaxf(sqrtf(sn), 1e-4f);
    mm[i]   = (sm == 0.0f) ? 1.0f : 0.0f;   // mean over 9 == 0 <=> sum == 0
}

// ---------------- K2: D = fd * bd^T  (M=N=2304, K=64), batched (fp32) ------
__global__ __launch_bounds__(256) void k_gemmD(const float* __restrict__ fd,
    const float* __restrict__ bd, float* __restrict__ D)
{
    int bi = blockIdx.z;
    int m0 = blockIdx.y*64, n0 = blockIdx.x*64;
    const float* A = fd + (size_t)bi*KL*KC;   // [m][k]
    const float* B = bd + (size_t)bi*KL*KC;   // [n][k]
    __shared__ float As[64][65];  // [k][m]
    __shared__ float Bs[64][65];  // [k][n]
    int t = threadIdx.x;
    #pragma unroll
    for (int i = 0; i < 16; i++) {
        int idx = t + i*256; int r = idx >> 6, c = idx & 63;
        As[c][r] = A[(size_t)(m0 + r)*KC + c];
        Bs[c][r] = B[(size_t)(n0 + r)*KC + c];
    }
    __syncthreads();
    int tx = t & 15, ty = t >> 4;
    float acc[4][4] = {};
    #pragma unroll 8
    for (int k = 0; k < 64; k++) {
        float a[4], bb[4];
        #pragma unroll
        for (int i = 0; i < 4; i++) a[i]  = As[k][ty*4 + i];
        #pragma unroll
        for (int j = 0; j < 4; j++) bb[j] = Bs[k][tx*4 + j];
        #pragma unroll
        for (int i = 0; i < 4; i++)
            #pragma unroll
            for (int j = 0; j < 4; j++) acc[i][j] += a[i]*bb[j];
    }
    for (int i = 0; i < 4; i++) {
        int m = m0 + ty*4 + i;
        for (int j = 0; j < 4; j++)
            D[((size_t)bi*KL + m)*KL + n0 + tx*4 + j] = acc[i][j];
    }
}

// ------ K3': fused diag9/norm + fuse conv #1 --------------------------------
// Output tile: 4 p-rows x 256 q-cols. Stage 1: S halo tile (6 x 258) in LDS.
// Flat-OOB halo entries set to 0 == reference's skipped taps.
__global__ __launch_bounds__(256) void k_fuse_a(const float* __restrict__ D,
    const float* __restrict__ rnrm, const float* __restrict__ fw,
    float* __restrict__ Y1)
{
    __shared__ float Sl[6][260];
    int bi = blockIdx.z;
    int p0 = blockIdx.y*4, q0 = blockIdx.x*256;
    const float* Db = D + (size_t)bi*KL*KL;
    int t = threadIdx.x;
    for (int i = t; i < 6*258; i += 256) {
        int r = i / 258, c = i - r*258;
        int pp = p0 - 1 + r, qq = q0 - 1 + c;
        float s = 0.f;
        if ((unsigned)pp < KL && (unsigned)qq < KL) {
            int py = pp / KHS, px = pp - py*KHS;
            int qy = qq / KHS, qx = qq - qy*KHS;
            float acc = 0.f;
            #pragma unroll
            for (int dy = -1; dy <= 1; dy++) {
                int yy = py + dy, vv = qy + dy;
                if ((unsigned)yy >= KHS || (unsigned)vv >= KHS) continue;
                #pragma unroll
                for (int dx = -1; dx <= 1; dx++) {
                    int xx = px + dx, uu = qx + dx;
                    if ((unsigned)xx >= KHS || (unsigned)uu >= KHS) continue;
                    acc += Db[(size_t)(yy*KHS + xx)*KL + vv*KHS + uu];
                }
            }
            s = acc * rnrm[bi*KL + qq];
        }
        Sl[r][c] = s;
    }
    __syncthreads();
    float w[9];
    #pragma unroll
    for (int i = 0; i < 9; i++) w[i] = fw[i];
    int c = t;
    int q = q0 + c;
    #pragma unroll
    for (int rr = 0; rr < 4; rr++) {
        int p = p0 + rr;
        float acc = 0.f;
        #pragma unroll
        for (int a = 0; a < 3; a++)
            #pragma unroll
            for (int b = 0; b < 3; b++)
                acc += w[a*3 + b] * Sl[rr + a][c + b];
        Y1[((size_t)bi*KL + p)*KL + q] = acc;
    }
}

// ------ K5': fused fuse conv #2 (transposed flat) + softmax -> bf16 ---------
// One block per output row p. 3 permuted source rows of Y1 staged in LDS.
__global__ __launch_bounds__(256) void k_fuse_b(const float* __restrict__ Y1,
    const float* __restrict__ fw, const float* __restrict__ mm,
    unsigned short* __restrict__ Ybf)
{
    __shared__ float rowb[3][KL];
    __shared__ float red[16];
    int p = blockIdx.x, bi = blockIdx.y;
    int y = p / KHS, x = p - y*KHS;
    int tp = x*KHS + y;
    int t = threadIdx.x;
    const float* Yb = Y1 + (size_t)bi*KL*KL;
    #pragma unroll
    for (int a = 0; a < 3; a++) {
        int t2 = tp + a - 1;
        float4* dst = (float4*)&rowb[a][0];
        if ((unsigned)t2 < KL) {
            int pr = (t2 % KHS)*KHS + t2/KHS;
            const float4* src = (const float4*)&Yb[(size_t)pr*KL];
            for (int i = t; i < KL/4; i += 256) dst[i] = src[i];
        } else {
            float4 z = {0.f,0.f,0.f,0.f};
            for (int i = t; i < KL/4; i += 256) dst[i] = z;
        }
    }
    float w[9];
    #pragma unroll
    for (int i = 0; i < 9; i++) w[i] = fw[i];
    __syncthreads();
    const float* mmb = mm + bi*KL;
    float vals[9];
    float lmax = -1e30f;
    #pragma unroll
    for (int i = 0; i < 9; i++) {
        int q = t + i*256;
        int v = q / KHS, u = q - v*KHS;
        int tq = u*KHS + v;
        float acc = 0.f;
        #pragma unroll
        for (int b = 0; b < 3; b++) {
            int s2 = tq + b - 1;
            if ((unsigned)s2 >= KL) continue;
            int qr = (s2 % KHS)*KHS + s2/KHS;
            acc += w[b]*rowb[0][qr] + w[3 + b]*rowb[1][qr] + w[6 + b]*rowb[2][qr];
        }
        float val = acc * mmb[q] * 10.0f;
        vals[i] = val;
        lmax = fmaxf(lmax, val);
    }
    #pragma unroll
    for (int off = 32; off > 0; off >>= 1) lmax = fmaxf(lmax, __shfl_down(lmax, off));
    if ((t & 63) == 0) red[t >> 6] = lmax;
    __syncthreads();
    if (t == 0) {
        float m = red[0];
        for (int i = 1; i < 4; i++) m = fmaxf(m, red[i]);
        red[0] = m;
    }
    __syncthreads();
    float bmax = red[0];
    float lsum = 0.f;
    #pragma unroll
    for (int i = 0; i < 9; i++) {
        float e = __expf(vals[i] - bmax);
        vals[i] = e;
        lsum += e;
    }
    #pragma unroll
    for (int off = 32; off > 0; off >>= 1) lsum += __shfl_down(lsum, off);
    if ((t & 63) == 0) red[8 + (t >> 6)] = lsum;
    __syncthreads();
    if (t == 0) {
        float s = red[8];
        for (int i = 1; i < 4; i++) s += red[8 + i];
        red[8] = s;
    }
    __syncthreads();
    float inv = 1.0f / red[8];
    unsigned short* orow = Ybf + ((size_t)bi*KL + p)*KL;
    #pragma unroll
    for (int i = 0; i < 9; i++) {
        int q = t + i*256;
        orow[q] = f2bf(vals[i]*inv*mmb[q]);
    }
}

// ---------------- KR: Rt[n][k] bf16, n=(ky,kx,c), k=q; vectorized over k ----
__global__ __launch_bounds__(256) void k_buildRt(const float* __restrict__ bsrc,
    unsigned short* __restrict__ Rt)
{
    int idx = blockIdx.x*256 + threadIdx.x;   // nb*1024*288
    int k8 = idx % 288;
    int rest = idx / 288;
    int n  = rest % 1024;
    int bi = rest / 1024;
    int jj = n >> 6, c = n & 63;
    int ky = jj >> 2, kx = jj & 3;
    int k0 = k8*8;
    bf16x8 vv;
    #pragma unroll
    for (int j = 0; j < 8; j++) {
        int q = k0 + j;
        int v = q / KHS, u = q % KHS;
        int ry = 2*v + ky - 1, rx = 2*u + kx - 1;
        float val = 0.f;
        if ((unsigned)ry < KHH && (unsigned)rx < KHH)
            val = bsrc[(((size_t)bi*KHH + ry)*KHH + rx)*KC + c];
        vv[j] = (short)f2bf(val);
    }
    *(bf16x8*)&Rt[((size_t)bi*1024 + n)*KL + k0] = vv;
}

// ---------------- K7: P = Y * Rt^T via bf16 MFMA ----------------------------
__global__ __launch_bounds__(256) void k_gemmP_mfma(const unsigned short* __restrict__ Y,
    const unsigned short* __restrict__ Rt, float* __restrict__ P)
{
    int bi = blockIdx.z;
    int m0 = blockIdx.y*128, n0 = blockIdx.x*128;
    const unsigned short* Yb = Y  + (size_t)bi*KL*KL;
    const unsigned short* Rb = Rt + (size_t)bi*1024*KL;
    __shared__ unsigned short As[128*40];   // rows padded to 40 bf16 (80 B)
    __shared__ unsigned short Bs[128*40];
    int t = threadIdx.x;
    int lane = t & 63, w = t >> 6;
    int wm = (w >> 1)*64, wn = (w & 1)*64;
    int l15 = lane & 15, quad = lane >> 4;
    f32x4 acc[4][4];
    #pragma unroll
    for (int i = 0; i < 4; i++)
        #pragma unroll
        for (int j = 0; j < 4; j++) acc[i][j] = (f32x4){0.f,0.f,0.f,0.f};

    for (int k0 = 0; k0 < KL; k0 += 32) {
        #pragma unroll
        for (int i = 0; i < 2; i++) {
            int slot = t + i*256;
            int r = slot >> 2, ch = slot & 3;
            bf16x8 va = *(const bf16x8*)&Yb[(size_t)(m0 + r)*KL + k0 + ch*8];
            *(bf16x8*)&As[r*40 + ch*8] = va;
            bf16x8 vb = *(const bf16x8*)&Rb[(size_t)(n0 + r)*KL + k0 + ch*8];
            *(bf16x8*)&Bs[r*40 + ch*8] = vb;
        }
        __syncthreads();
        bf16x8 af[4], bf[4];
        #pragma unroll
        for (int mi = 0; mi < 4; mi++)
            af[mi] = *(const bf16x8*)&As[(wm + mi*16 + l15)*40 + quad*8];
        #pragma unroll
        for (int ni = 0; ni < 4; ni++)
            bf[ni] = *(const bf16x8*)&Bs[(wn + ni*16 + l15)*40 + quad*8];
        #pragma unroll
        for (int mi = 0; mi < 4; mi++)
            #pragma unroll
            for (int ni = 0; ni < 4; ni++)
                acc[mi][ni] = __builtin_amdgcn_mfma_f32_16x16x32_bf16(
                    af[mi], bf[ni], acc[mi][ni], 0, 0, 0);
        __syncthreads();
    }
    #pragma unroll
    for (int mi = 0; mi < 4; mi++) {
        #pragma unroll
        for (int ni = 0; ni < 4; ni++) {
            int col = n0 + wn + ni*16 + l15;
            #pragma unroll
            for (int r = 0; r < 4; r++) {
                int row = m0 + wm + mi*16 + quad*4 + r;
                P[((size_t)bi*KL + row)*1024 + col] = acc[mi][ni][r];
            }
        }
    }
}

// ---------------- K8: overlap-add (adjoint of stride-2 4x4 SAME conv), /4 ---
__global__ __launch_bounds__(256) void k_overlap(const float* __restrict__ P,
    float* __restrict__ out)
{
    size_t gid = (size_t)blockIdx.x*256 + threadIdx.x;   // nb*96*96*64
    int c = gid & 63;
    size_t r = gid >> 6;
    int ix = (int)(r % KHH); r /= KHH;
    int iy = (int)(r % KHH);
    int bi = (int)(r / KHH);
    float acc = 0.f;
    #pragma unroll
    for (int sy = 0; sy < 2; sy++) {
        int ky = (iy & 1) ? (sy*2) : (sy*2 + 1);
        int yp = (iy + 1 - ky) >> 1;
        if ((unsigned)yp >= KHS) continue;
        #pragma unroll
        for (int sx = 0; sx < 2; sx++) {
            int kx = (ix & 1) ? (sx*2) : (sx*2 + 1);
            int xp = (ix + 1 - kx) >> 1;
            if ((unsigned)xp >= KHS) continue;
            acc += P[(((size_t)bi*KL + yp*KHS + xp)*16 + (ky*4 + kx))*64 + c];
        }
    }
    out[gid] = 0.25f * acc;
}

extern "C" void kernel_launch(void* const* d_in, const int* in_sizes, int n_in,
                              void* d_out, int out_size, void* d_ws, size_t ws_size,
                              hipStream_t stream)
{
    const float* f    = (const float*)d_in[0];
    const float* b    = (const float*)d_in[1];
    const float* mask = (const float*)d_in[2];
    const float* fw   = (const float*)d_in[3];
    float* out = (float*)d_out;

    auto need = [](int nbc) -> size_t {
        return (size_t)nbc * (2ull*KL*KC + 4ull*KL + 2ull*(size_t)KL*KL) * 4ull;
    };
    int nbc = 4;
    if (need(nbc) > ws_size) nbc = 2;
    if (need(nbc) > ws_size) nbc = 1;

    for (int bi0 = 0; bi0 < 4; bi0 += nbc) {
        int nb = (4 - bi0 < nbc) ? (4 - bi0) : nbc;
        const float* fc = f    + (size_t)bi0*KHH*KHH*KC;
        const float* bc = b    + (size_t)bi0*KHH*KHH*KC;
        const float* mc = mask + (size_t)bi0*KHH*KHH;
        float* outc = out + (size_t)bi0*KHH*KHH*KC;

        float* w    = (float*)d_ws;
        float* fd   = w;  w += (size_t)nbc*KL*KC;
        float* bd   = w;  w += (size_t)nbc*KL*KC;
        float* nbuf = w;  w += (size_t)nbc*KL;
        float* mdd  = w;  w += (size_t)nbc*KL;
        float* rnrm = w;  w += (size_t)nbc*KL;
        float* mmb  = w;  w += (size_t)nbc*KL;
        float* bufA = w;  w += (size_t)nbc*KL*KL;
        float* bufB = w;
        // bufA: D (fp32) -> later Ybf (bf16, first half) + Pbuf (fp32, second half)
        // bufB: Y1 (fp32) -> later Rt (bf16)
        unsigned short* Ybf = (unsigned short*)bufA;
        float* Pbuf = bufA + (size_t)nbc*KL*KL/2;
        unsigned short* Rtb = (unsigned short*)bufB;

        k_prep    <<<nb*KL, 64, 0, stream>>>(fc, bc, mc, fd, bd, nbuf, mdd);
        k_normmask<<<(nb*KL)/256, 256, 0, stream>>>(nbuf, mdd, rnrm, mmb);
        k_gemmD   <<<dim3(36, 36, nb), 256, 0, stream>>>(fd, bd, bufA);
        // fused diag9/norm + fuse1: reads D (bufA), writes Y1 (bufB)
        k_fuse_a  <<<dim3(9, 576, nb), 256, 0, stream>>>(bufA, rnrm, fw, bufB);
        // fused fuse2 + softmax: reads Y1 (bufB), writes bf16 Y (bufA)
        k_fuse_b  <<<dim3(KL, nb), 256, 0, stream>>>(bufB, fw, mmb, Ybf);
        // bufB now free -> build Rt there
        k_buildRt <<<(nb*1024*288)/256, 256, 0, stream>>>(bc, Rtb);
        k_gemmP_mfma<<<dim3(8, 18, nb), 256, 0, stream>>>(Ybf, Rtb, Pbuf);
        k_overlap <<<nb*KL, 256, 0, stream>>>(Pbuf, outc);
    }
}

// Round 5
// 446.043 us; speedup vs baseline: 2.6844x; 1.2008x over previous
//
#include <hip/hip_runtime.h>
#include <hip/hip_bf16.h>

#define KL  2304   // 48*48
#define KC  64
#define KHS 48
#define KHH 96
#define OFFX (KL + 1)          // flat offset for (p+1,q+1)
#define OFFY (KHS*(KL + 1))    // flat offset for (p+48,q+48) = 110640

typedef __attribute__((ext_vector_type(8))) short bf16x8;
typedef __attribute__((ext_vector_type(4))) float f32x4;

static __device__ inline unsigned short f2bf(float x) {
    __hip_bfloat16 h = __float2bfloat16(x);
    return *reinterpret_cast<unsigned short*>(&h);
}

// ---------------- K0: downsample f,b; per-pixel |bd|^2; downsampled mask ----
__global__ __launch_bounds__(64) void k_prep(const float* __restrict__ f,
    const float* __restrict__ bsrc, const float* __restrict__ mask,
    float* __restrict__ fd, float* __restrict__ bd,
    float* __restrict__ nbuf, float* __restrict__ mdd)
{
    int blk = blockIdx.x;              // nb*KL blocks
    int p = blk % KL, bi = blk / KL;
    int y = p / KHS, x = p % KHS;
    int fy = 2*y + 1, fx = 2*x + 1;
    int c = threadIdx.x;
    size_t src = (((size_t)bi*KHH + fy)*KHH + fx)*KC + c;
    float fv = f[src], bv = bsrc[src];
    size_t dst = ((size_t)bi*KL + p)*KC + c;
    fd[dst] = fv;
    bd[dst] = bv;
    float s = bv*bv;
    #pragma unroll
    for (int off = 32; off > 0; off >>= 1) s += __shfl_down(s, off);
    if (c == 0) {
        nbuf[bi*KL + p] = s;
        mdd[bi*KL + p]  = mask[((size_t)bi*KHH + fy)*KHH + fx];
    }
}

// ------- K1: rnrm[q] = 1/max(sqrt(9-tap sum nb),1e-4); mm from mask --------
__global__ __launch_bounds__(256) void k_normmask(const float* __restrict__ nbuf,
    const float* __restrict__ mdd, float* __restrict__ rnrm, float* __restrict__ mm)
{
    int i = blockIdx.x*256 + threadIdx.x;   // nb*KL
    int q = i % KL, bi = i / KL;
    int v = q / KHS, u = q % KHS;
    float sn = 0.f, sm = 0.f;
    for (int dy = -1; dy <= 1; dy++) {
        int vv = v + dy; if ((unsigned)vv >= KHS) continue;
        for (int dx = -1; dx <= 1; dx++) {
            int uu = u + dx; if ((unsigned)uu >= KHS) continue;
            sn += nbuf[bi*KL + vv*KHS + uu];
            sm += mdd[bi*KL + vv*KHS + uu];
        }
    }
    rnrm[i] = 1.0f / fmaxf(sqrtf(sn), 1e-4f);
    mm[i]   = (sm == 0.0f) ? 1.0f : 0.0f;   // mean over 9 == 0 <=> sum == 0
}

// ---------------- K2: D = fd * bd^T  (M=N=2304, K=64), batched (fp32) ------
__global__ __launch_bounds__(256) void k_gemmD(const float* __restrict__ fd,
    const float* __restrict__ bd, float* __restrict__ D)
{
    int bi = blockIdx.z;
    int m0 = blockIdx.y*64, n0 = blockIdx.x*64;
    const float* A = fd + (size_t)bi*KL*KC;   // [m][k]
    const float* B = bd + (size_t)bi*KL*KC;   // [n][k]
    __shared__ float As[64][65];  // [k][m]
    __shared__ float Bs[64][65];  // [k][n]
    int t = threadIdx.x;
    #pragma unroll
    for (int i = 0; i < 16; i++) {
        int idx = t + i*256; int r = idx >> 6, c = idx & 63;
        As[c][r] = A[(size_t)(m0 + r)*KC + c];
        Bs[c][r] = B[(size_t)(n0 + r)*KC + c];
    }
    __syncthreads();
    int tx = t & 15, ty = t >> 4;
    float acc[4][4] = {};
    #pragma unroll 8
    for (int k = 0; k < 64; k++) {
        float a[4], bb[4];
        #pragma unroll
        for (int i = 0; i < 4; i++) a[i]  = As[k][ty*4 + i];
        #pragma unroll
        for (int j = 0; j < 4; j++) bb[j] = Bs[k][tx*4 + j];
        #pragma unroll
        for (int i = 0; i < 4; i++)
            #pragma unroll
            for (int j = 0; j < 4; j++) acc[i][j] += a[i]*bb[j];
    }
    for (int i = 0; i < 4; i++) {
        int m = m0 + ty*4 + i;
        for (int j = 0; j < 4; j++)
            D[((size_t)bi*KL + m)*KL + n0 + tx*4 + j] = acc[i][j];
    }
}

// ------ K3a: x-diagonal 3-tap: T[p,q] = sum_dx D[p+dx, q+dx] ----------------
// Flat offsets +-(KL+1); validity depends only on px,qx.
__global__ __launch_bounds__(256) void k_diagx(const float* __restrict__ D,
    float* __restrict__ T)
{
    int blk = blockIdx.x;          // nb*KL
    int p = blk % KL, bi = blk / KL;
    int px = p % KHS;
    const float* Dp = D + (size_t)bi*KL*KL + (size_t)p*KL;
    float* Tp = T + (size_t)bi*KL*KL + (size_t)p*KL;
    bool okm = (px >= 1), okp = (px <= KHS - 2);
    int t = threadIdx.x;
    #pragma unroll
    for (int i = 0; i < 9; i++) {
        int q = t + i*256;
        int qx = q % KHS;
        float s = Dp[q];
        if (okm && qx >= 1)       s += Dp[q - OFFX];
        if (okp && qx <= KHS - 2) s += Dp[q + OFFX];
        Tp[q] = s;
    }
}

// ------ K3b: y-diagonal 3-tap * rnrm + fuse conv #1 -------------------------
// Tile: 8 p-rows x 256 q-cols. S halo (10 x 258) in LDS. Y-taps at flat
// offsets +-OFFY with pure flat-range validity checks (no div/mod).
__global__ __launch_bounds__(256) void k_fuse_a2(const float* __restrict__ T,
    const float* __restrict__ rnrm, const float* __restrict__ fw,
    float* __restrict__ Y1)
{
    __shared__ float Sl[10][260];
    int bi = blockIdx.z;
    int p0 = blockIdx.y*8, q0 = blockIdx.x*256;
    const float* Tb = T + (size_t)bi*KL*KL;
    const float* rn = rnrm + bi*KL;
    int t = threadIdx.x;
    for (int i = t; i < 10*258; i += 256) {
        int r = i / 258, c = i - r*258;
        int pp = p0 - 1 + r, qq = q0 - 1 + c;
        float s = 0.f;
        if ((unsigned)pp < KL && (unsigned)qq < KL) {
            size_t base = (size_t)pp*KL + qq;
            float acc = Tb[base];
            if (pp >= KHS && qq >= KHS)           acc += Tb[base - OFFY];
            if (pp < KL - KHS && qq < KL - KHS)   acc += Tb[base + OFFY];
            s = acc * rn[qq];
        }
        Sl[r][c] = s;
    }
    __syncthreads();
    float w[9];
    #pragma unroll
    for (int i = 0; i < 9; i++) w[i] = fw[i];
    int c = t, q = q0 + c;
    float h0[10], h1[10], h2[10];
    #pragma unroll
    for (int r = 0; r < 10; r++) {
        float s0 = Sl[r][c], s1 = Sl[r][c+1], s2 = Sl[r][c+2];
        h0[r] = w[0]*s0 + w[1]*s1 + w[2]*s2;
        h1[r] = w[3]*s0 + w[4]*s1 + w[5]*s2;
        h2[r] = w[6]*s0 + w[7]*s1 + w[8]*s2;
    }
    #pragma unroll
    for (int rr = 0; rr < 8; rr++) {
        Y1[((size_t)bi*KL + p0 + rr)*KL + q] = h0[rr] + h1[rr+1] + h2[rr+2];
    }
}

// ------ K5': fused fuse conv #2 (transposed flat) + softmax -> bf16 ---------
__global__ __launch_bounds__(256) void k_fuse_b(const float* __restrict__ Y1,
    const float* __restrict__ fw, const float* __restrict__ mm,
    unsigned short* __restrict__ Ybf)
{
    __shared__ float rowb[3][KL];
    __shared__ float red[16];
    int p = blockIdx.x, bi = blockIdx.y;
    int y = p / KHS, x = p - y*KHS;
    int tp = x*KHS + y;
    int t = threadIdx.x;
    const float* Yb = Y1 + (size_t)bi*KL*KL;
    #pragma unroll
    for (int a = 0; a < 3; a++) {
        int t2 = tp + a - 1;
        float4* dst = (float4*)&rowb[a][0];
        if ((unsigned)t2 < KL) {
            int pr = (t2 % KHS)*KHS + t2/KHS;
            const float4* src = (const float4*)&Yb[(size_t)pr*KL];
            for (int i = t; i < KL/4; i += 256) dst[i] = src[i];
        } else {
            float4 z = {0.f,0.f,0.f,0.f};
            for (int i = t; i < KL/4; i += 256) dst[i] = z;
        }
    }
    float w[9];
    #pragma unroll
    for (int i = 0; i < 9; i++) w[i] = fw[i];
    __syncthreads();
    const float* mmb = mm + bi*KL;
    float vals[9];
    float lmax = -1e30f;
    #pragma unroll
    for (int i = 0; i < 9; i++) {
        int q = t + i*256;
        int v = q / KHS, u = q - v*KHS;
        int tq = u*KHS + v;
        float acc = 0.f;
        #pragma unroll
        for (int b = 0; b < 3; b++) {
            int s2 = tq + b - 1;
            if ((unsigned)s2 >= KL) continue;
            int qr = (s2 % KHS)*KHS + s2/KHS;
            acc += w[b]*rowb[0][qr] + w[3 + b]*rowb[1][qr] + w[6 + b]*rowb[2][qr];
        }
        float val = acc * mmb[q] * 10.0f;
        vals[i] = val;
        lmax = fmaxf(lmax, val);
    }
    #pragma unroll
    for (int off = 32; off > 0; off >>= 1) lmax = fmaxf(lmax, __shfl_down(lmax, off));
    if ((t & 63) == 0) red[t >> 6] = lmax;
    __syncthreads();
    if (t == 0) {
        float m = red[0];
        for (int i = 1; i < 4; i++) m = fmaxf(m, red[i]);
        red[0] = m;
    }
    __syncthreads();
    float bmax = red[0];
    float lsum = 0.f;
    #pragma unroll
    for (int i = 0; i < 9; i++) {
        float e = __expf(vals[i] - bmax);
        vals[i] = e;
        lsum += e;
    }
    #pragma unroll
    for (int off = 32; off > 0; off >>= 1) lsum += __shfl_down(lsum, off);
    if ((t & 63) == 0) red[8 + (t >> 6)] = lsum;
    __syncthreads();
    if (t == 0) {
        float s = red[8];
        for (int i = 1; i < 4; i++) s += red[8 + i];
        red[8] = s;
    }
    __syncthreads();
    float inv = 1.0f / red[8];
    unsigned short* orow = Ybf + ((size_t)bi*KL + p)*KL;
    #pragma unroll
    for (int i = 0; i < 9; i++) {
        int q = t + i*256;
        orow[q] = f2bf(vals[i]*inv*mmb[q]);
    }
}

// ---------------- KR: Rt[n][k] bf16, n=(ky,kx,c), k=q; vectorized over k ----
__global__ __launch_bounds__(256) void k_buildRt(const float* __restrict__ bsrc,
    unsigned short* __restrict__ Rt)
{
    int idx = blockIdx.x*256 + threadIdx.x;   // nb*1024*288
    int k8 = idx % 288;
    int rest = idx / 288;
    int n  = rest % 1024;
    int bi = rest / 1024;
    int jj = n >> 6, c = n & 63;
    int ky = jj >> 2, kx = jj & 3;
    int k0 = k8*8;
    bf16x8 vv;
    #pragma unroll
    for (int j = 0; j < 8; j++) {
        int q = k0 + j;
        int v = q / KHS, u = q % KHS;
        int ry = 2*v + ky - 1, rx = 2*u + kx - 1;
        float val = 0.f;
        if ((unsigned)ry < KHH && (unsigned)rx < KHH)
            val = bsrc[(((size_t)bi*KHH + ry)*KHH + rx)*KC + c];
        vv[j] = (short)f2bf(val);
    }
    *(bf16x8*)&Rt[((size_t)bi*1024 + n)*KL + k0] = vv;
}

// ---------------- K7: P = Y * Rt^T via bf16 MFMA ----------------------------
__global__ __launch_bounds__(256) void k_gemmP_mfma(const unsigned short* __restrict__ Y,
    const unsigned short* __restrict__ Rt, float* __restrict__ P)
{
    int bi = blockIdx.z;
    int m0 = blockIdx.y*128, n0 = blockIdx.x*128;
    const unsigned short* Yb = Y  + (size_t)bi*KL*KL;
    const unsigned short* Rb = Rt + (size_t)bi*1024*KL;
    __shared__ unsigned short As[128*40];   // rows padded to 40 bf16 (80 B)
    __shared__ unsigned short Bs[128*40];
    int t = threadIdx.x;
    int lane = t & 63, w = t >> 6;
    int wm = (w >> 1)*64, wn = (w & 1)*64;
    int l15 = lane & 15, quad = lane >> 4;
    f32x4 acc[4][4];
    #pragma unroll
    for (int i = 0; i < 4; i++)
        #pragma unroll
        for (int j = 0; j < 4; j++) acc[i][j] = (f32x4){0.f,0.f,0.f,0.f};

    for (int k0 = 0; k0 < KL; k0 += 32) {
        #pragma unroll
        for (int i = 0; i < 2; i++) {
            int slot = t + i*256;
            int r = slot >> 2, ch = slot & 3;
            bf16x8 va = *(const bf16x8*)&Yb[(size_t)(m0 + r)*KL + k0 + ch*8];
            *(bf16x8*)&As[r*40 + ch*8] = va;
            bf16x8 vb = *(const bf16x8*)&Rb[(size_t)(n0 + r)*KL + k0 + ch*8];
            *(bf16x8*)&Bs[r*40 + ch*8] = vb;
        }
        __syncthreads();
        bf16x8 af[4], bf[4];
        #pragma unroll
        for (int mi = 0; mi < 4; mi++)
            af[mi] = *(const bf16x8*)&As[(wm + mi*16 + l15)*40 + quad*8];
        #pragma unroll
        for (int ni = 0; ni < 4; ni++)
            bf[ni] = *(const bf16x8*)&Bs[(wn + ni*16 + l15)*40 + quad*8];
        #pragma unroll
        for (int mi = 0; mi < 4; mi++)
            #pragma unroll
            for (int ni = 0; ni < 4; ni++)
                acc[mi][ni] = __builtin_amdgcn_mfma_f32_16x16x32_bf16(
                    af[mi], bf[ni], acc[mi][ni], 0, 0, 0);
        __syncthreads();
    }
    #pragma unroll
    for (int mi = 0; mi < 4; mi++) {
        #pragma unroll
        for (int ni = 0; ni < 4; ni++) {
            int col = n0 + wn + ni*16 + l15;
            #pragma unroll
            for (int r = 0; r < 4; r++) {
                int row = m0 + wm + mi*16 + quad*4 + r;
                P[((size_t)bi*KL + row)*1024 + col] = acc[mi][ni][r];
            }
        }
    }
}

// ---------------- K8: overlap-add (adjoint of stride-2 4x4 SAME conv), /4 ---
__global__ __launch_bounds__(256) void k_overlap(const float* __restrict__ P,
    float* __restrict__ out)
{
    size_t gid = (size_t)blockIdx.x*256 + threadIdx.x;   // nb*96*96*64
    int c = gid & 63;
    size_t r = gid >> 6;
    int ix = (int)(r % KHH); r /= KHH;
    int iy = (int)(r % KHH);
    int bi = (int)(r / KHH);
    float acc = 0.f;
    #pragma unroll
    for (int sy = 0; sy < 2; sy++) {
        int ky = (iy & 1) ? (sy*2) : (sy*2 + 1);
        int yp = (iy + 1 - ky) >> 1;
        if ((unsigned)yp >= KHS) continue;
        #pragma unroll
        for (int sx = 0; sx < 2; sx++) {
            int kx = (ix & 1) ? (sx*2) : (sx*2 + 1);
            int xp = (ix + 1 - kx) >> 1;
            if ((unsigned)xp >= KHS) continue;
            acc += P[(((size_t)bi*KL + yp*KHS + xp)*16 + (ky*4 + kx))*64 + c];
        }
    }
    out[gid] = 0.25f * acc;
}

extern "C" void kernel_launch(void* const* d_in, const int* in_sizes, int n_in,
                              void* d_out, int out_size, void* d_ws, size_t ws_size,
                              hipStream_t stream)
{
    const float* f    = (const float*)d_in[0];
    const float* b    = (const float*)d_in[1];
    const float* mask = (const float*)d_in[2];
    const float* fw   = (const float*)d_in[3];
    float* out = (float*)d_out;

    auto need = [](int nbc) -> size_t {
        return (size_t)nbc * (2ull*KL*KC + 4ull*KL + 2ull*(size_t)KL*KL) * 4ull;
    };
    int nbc = 4;
    if (need(nbc) > ws_size) nbc = 2;
    if (need(nbc) > ws_size) nbc = 1;

    for (int bi0 = 0; bi0 < 4; bi0 += nbc) {
        int nb = (4 - bi0 < nbc) ? (4 - bi0) : nbc;
        const float* fc = f    + (size_t)bi0*KHH*KHH*KC;
        const float* bc = b    + (size_t)bi0*KHH*KHH*KC;
        const float* mc = mask + (size_t)bi0*KHH*KHH;
        float* outc = out + (size_t)bi0*KHH*KHH*KC;

        float* w    = (float*)d_ws;
        float* fd   = w;  w += (size_t)nbc*KL*KC;
        float* bd   = w;  w += (size_t)nbc*KL*KC;
        float* nbuf = w;  w += (size_t)nbc*KL;
        float* mdd  = w;  w += (size_t)nbc*KL;
        float* rnrm = w;  w += (size_t)nbc*KL;
        float* mmb  = w;  w += (size_t)nbc*KL;
        float* bufA = w;  w += (size_t)nbc*KL*KL;
        float* bufB = w;
        // bufA: D -> Y1 -> P ;  bufB: T -> [Ybf bf16 | Rt bf16]
        unsigned short* Ybf = (unsigned short*)bufB;
        unsigned short* Rtb = Ybf + (size_t)nbc*KL*KL;
        float* Pbuf = bufA;

        k_prep    <<<nb*KL, 64, 0, stream>>>(fc, bc, mc, fd, bd, nbuf, mdd);
        k_normmask<<<(nb*KL)/256, 256, 0, stream>>>(nbuf, mdd, rnrm, mmb);
        k_gemmD   <<<dim3(36, 36, nb), 256, 0, stream>>>(fd, bd, bufA);
        // x-diagonal 3-tap: D (bufA) -> T (bufB)
        k_diagx   <<<nb*KL, 256, 0, stream>>>(bufA, bufB);
        // y-diagonal 3-tap * rnrm + fuse1: T (bufB) -> Y1 (bufA)
        k_fuse_a2 <<<dim3(9, 288, nb), 256, 0, stream>>>(bufB, rnrm, fw, bufA);
        // fuse2 + softmax: Y1 (bufA) -> Ybf (bufB, bf16)
        k_fuse_b  <<<dim3(KL, nb), 256, 0, stream>>>(bufA, fw, mmb, Ybf);
        k_buildRt <<<(nb*1024*288)/256, 256, 0, stream>>>(bc, Rtb);
        k_gemmP_mfma<<<dim3(8, 18, nb), 256, 0, stream>>>(Ybf, Rtb, Pbuf);
        k_overlap <<<nb*KL, 256, 0, stream>>>(Pbuf, outc);
    }
}

// Round 6
// 415.252 us; speedup vs baseline: 2.8835x; 1.0742x over previous
//
#include <hip/hip_runtime.h>
#include <hip/hip_bf16.h>

#define KL  2304   // 48*48
#define KC  64
#define KHS 48
#define KHH 96
#define OFFY (KHS*(KL + 1))    // flat offset for (p+48,q+48)

typedef __attribute__((ext_vector_type(8))) short bf16x8;
typedef __attribute__((ext_vector_type(4))) float f32x4;

static __device__ inline unsigned short f2bf(float x) {
    __hip_bfloat16 h = __float2bfloat16(x);
    return *reinterpret_cast<unsigned short*>(&h);
}
static __device__ inline float bf2f(unsigned short u) {
    unsigned v = ((unsigned)u) << 16;
    return __uint_as_float(v);
}

// ---------------- K0: downsample f,b; per-pixel |bd|^2; downsampled mask ----
__global__ __launch_bounds__(64) void k_prep(const float* __restrict__ f,
    const float* __restrict__ bsrc, const float* __restrict__ mask,
    float* __restrict__ fd, float* __restrict__ bd,
    float* __restrict__ nbuf, float* __restrict__ mdd)
{
    int blk = blockIdx.x;              // nb*KL blocks
    int p = blk % KL, bi = blk / KL;
    int y = p / KHS, x = p % KHS;
    int fy = 2*y + 1, fx = 2*x + 1;
    int c = threadIdx.x;
    size_t src = (((size_t)bi*KHH + fy)*KHH + fx)*KC + c;
    float fv = f[src], bv = bsrc[src];
    size_t dst = ((size_t)bi*KL + p)*KC + c;
    fd[dst] = fv;
    bd[dst] = bv;
    float s = bv*bv;
    #pragma unroll
    for (int off = 32; off > 0; off >>= 1) s += __shfl_down(s, off);
    if (c == 0) {
        nbuf[bi*KL + p] = s;
        mdd[bi*KL + p]  = mask[((size_t)bi*KHH + fy)*KHH + fx];
    }
}

// ------- K1: rnrm[q] = 1/max(sqrt(9-tap sum nb),1e-4); mm from mask --------
__global__ __launch_bounds__(256) void k_normmask(const float* __restrict__ nbuf,
    const float* __restrict__ mdd, float* __restrict__ rnrm, float* __restrict__ mm)
{
    int i = blockIdx.x*256 + threadIdx.x;   // nb*KL
    int q = i % KL, bi = i / KL;
    int v = q / KHS, u = q % KHS;
    float sn = 0.f, sm = 0.f;
    for (int dy = -1; dy <= 1; dy++) {
        int vv = v + dy; if ((unsigned)vv >= KHS) continue;
        for (int dx = -1; dx <= 1; dx++) {
            int uu = u + dx; if ((unsigned)uu >= KHS) continue;
            sn += nbuf[bi*KL + vv*KHS + uu];
            sm += mdd[bi*KL + vv*KHS + uu];
        }
    }
    rnrm[i] = 1.0f / fmaxf(sqrtf(sn), 1e-4f);
    mm[i]   = (sm == 0.0f) ? 1.0f : 0.0f;
}

// ------ K2': build split-bf16 x-shift-augmented operands, K=576 -------------
// k = seg*192 + dxi*64 + c, seg: {Ah*Bh, Ah*Bl, Al*Bh}, dxi: shift dx-1.
// Zeroed when px+dxi-1 leaves [0,48) (kills invalid diagonal taps).
__global__ __launch_bounds__(64) void k_build_hilo(const float* __restrict__ fd,
    const float* __restrict__ bd, unsigned short* __restrict__ Ahat,
    unsigned short* __restrict__ Bhat)
{
    int blk = blockIdx.x;              // nb*KL
    int p = blk % KL, bi = blk / KL;
    int c = threadIdx.x;
    int px = p % KHS;
    unsigned short* Ap = Ahat + ((size_t)bi*KL + p)*576;
    unsigned short* Bp = Bhat + ((size_t)bi*KL + p)*576;
    #pragma unroll
    for (int dxi = 0; dxi < 3; dxi++) {
        int xx = px + dxi - 1;
        float av = 0.f, bv = 0.f;
        if ((unsigned)xx < KHS) {
            int pp = p + dxi - 1;
            av = fd[((size_t)bi*KL + pp)*KC + c];
            bv = bd[((size_t)bi*KL + pp)*KC + c];
        }
        unsigned short ah = f2bf(av);
        unsigned short al = f2bf(av - bf2f(ah));
        unsigned short bh = f2bf(bv);
        unsigned short bl = f2bf(bv - bf2f(bh));
        Ap[0*192 + dxi*64 + c] = ah;
        Ap[1*192 + dxi*64 + c] = ah;
        Ap[2*192 + dxi*64 + c] = al;
        Bp[0*192 + dxi*64 + c] = bh;
        Bp[1*192 + dxi*64 + c] = bl;
        Bp[2*192 + dxi*64 + c] = bh;
    }
}

// ------ MFMA GEMM template: C = A * B^T, A[M][K], B[N][K] bf16, C fp32 ------
// 128x128 tile, BK=32. global_load_lds width=16 staging; unpadded 64 B LDS
// rows with chunk-XOR swizzle (ch ^ (row>>2)&3): staging conflict-free,
// fragment ds_read_b128 2-way (free).
template<int KDIM>
__global__ __launch_bounds__(256) void k_mfma_bt(const unsigned short* __restrict__ A,
    const unsigned short* __restrict__ B, float* __restrict__ C,
    int Ncols, size_t sA, size_t sB, size_t sC)
{
    int bi = blockIdx.z;
    int n0 = blockIdx.x*128, m0 = blockIdx.y*128;
    const unsigned short* Ab = A + (size_t)bi*sA;
    const unsigned short* Bb = B + (size_t)bi*sB;
    __shared__ unsigned short As[128*32];
    __shared__ unsigned short Bs[128*32];
    int t = threadIdx.x;
    int lane = t & 63, w = t >> 6;
    int l15 = lane & 15, quad = lane >> 4;
    int swf = (l15 >> 2) & 3;              // fragment-read swizzle
    int wm = (w >> 1)*64, wn = (w & 1)*64;
    int srow = lane >> 2;                  // staging: 4 lanes per 64 B row
    int ch = lane & 3;
    f32x4 acc[4][4];
    #pragma unroll
    for (int i = 0; i < 4; i++)
        #pragma unroll
        for (int j = 0; j < 4; j++) acc[i][j] = (f32x4){0.f,0.f,0.f,0.f};

    for (int k0 = 0; k0 < KDIM; k0 += 32) {
        #pragma unroll
        for (int i = 0; i < 2; i++) {
            int rbase = w*32 + i*16;
            int r = rbase + srow;
            int cs = (ch ^ ((r >> 2) & 3))*8;
            const unsigned short* ga = &Ab[(size_t)(m0 + r)*KDIM + k0 + cs];
            __builtin_amdgcn_global_load_lds(
                (const __attribute__((address_space(1))) void*)ga,
                (__attribute__((address_space(3))) void*)&As[rbase*32], 16, 0, 0);
            const unsigned short* gb = &Bb[(size_t)(n0 + r)*KDIM + k0 + cs];
            __builtin_amdgcn_global_load_lds(
                (const __attribute__((address_space(1))) void*)gb,
                (__attribute__((address_space(3))) void*)&Bs[rbase*32], 16, 0, 0);
        }
        __syncthreads();
        bf16x8 af[4], bfr[4];
        #pragma unroll
        for (int mi = 0; mi < 4; mi++)
            af[mi] = *(const bf16x8*)&As[(wm + mi*16 + l15)*32 + ((quad ^ swf)*8)];
        #pragma unroll
        for (int ni = 0; ni < 4; ni++)
            bfr[ni] = *(const bf16x8*)&Bs[(wn + ni*16 + l15)*32 + ((quad ^ swf)*8)];
        #pragma unroll
        for (int mi = 0; mi < 4; mi++)
            #pragma unroll
            for (int ni = 0; ni < 4; ni++)
                acc[mi][ni] = __builtin_amdgcn_mfma_f32_16x16x32_bf16(
                    af[mi], bfr[ni], acc[mi][ni], 0, 0, 0);
        __syncthreads();
    }
    #pragma unroll
    for (int mi = 0; mi < 4; mi++)
        #pragma unroll
        for (int ni = 0; ni < 4; ni++) {
            int col = n0 + wn + ni*16 + l15;
            #pragma unroll
            for (int r = 0; r < 4; r++) {
                int row = m0 + wm + mi*16 + quad*4 + r;
                C[(size_t)bi*sC + (size_t)row*Ncols + col] = acc[mi][ni][r];
            }
        }
}

// ------ K3b: y-diagonal 3-tap * rnrm + fuse conv #1 -------------------------
__global__ __launch_bounds__(256) void k_fuse_a2(const float* __restrict__ T,
    const float* __restrict__ rnrm, const float* __restrict__ fw,
    float* __restrict__ Y1)
{
    __shared__ float Sl[10][260];
    int bi = blockIdx.z;
    int p0 = blockIdx.y*8, q0 = blockIdx.x*256;
    const float* Tb = T + (size_t)bi*KL*KL;
    const float* rn = rnrm + bi*KL;
    int t = threadIdx.x;
    for (int i = t; i < 10*258; i += 256) {
        int r = i / 258, c = i - r*258;
        int pp = p0 - 1 + r, qq = q0 - 1 + c;
        float s = 0.f;
        if ((unsigned)pp < KL && (unsigned)qq < KL) {
            size_t base = (size_t)pp*KL + qq;
            float acc = Tb[base];
            if (pp >= KHS && qq >= KHS)           acc += Tb[base - OFFY];
            if (pp < KL - KHS && qq < KL - KHS)   acc += Tb[base + OFFY];
            s = acc * rn[qq];
        }
        Sl[r][c] = s;
    }
    __syncthreads();
    float w[9];
    #pragma unroll
    for (int i = 0; i < 9; i++) w[i] = fw[i];
    int c = t, q = q0 + c;
    float h0[10], h1[10], h2[10];
    #pragma unroll
    for (int r = 0; r < 10; r++) {
        float s0 = Sl[r][c], s1 = Sl[r][c+1], s2 = Sl[r][c+2];
        h0[r] = w[0]*s0 + w[1]*s1 + w[2]*s2;
        h1[r] = w[3]*s0 + w[4]*s1 + w[5]*s2;
        h2[r] = w[6]*s0 + w[7]*s1 + w[8]*s2;
    }
    #pragma unroll
    for (int rr = 0; rr < 8; rr++) {
        Y1[((size_t)bi*KL + p0 + rr)*KL + q] = h0[rr] + h1[rr+1] + h2[rr+2];
    }
}

// ------ K5': fused fuse conv #2 (transposed flat) + softmax -> bf16 ---------
__global__ __launch_bounds__(256) void k_fuse_b(const float* __restrict__ Y1,
    const float* __restrict__ fw, const float* __restrict__ mm,
    unsigned short* __restrict__ Ybf)
{
    __shared__ float rowb[3][KL];
    __shared__ float red[16];
    int p = blockIdx.x, bi = blockIdx.y;
    int y = p / KHS, x = p - y*KHS;
    int tp = x*KHS + y;
    int t = threadIdx.x;
    const float* Yb = Y1 + (size_t)bi*KL*KL;
    #pragma unroll
    for (int a = 0; a < 3; a++) {
        int t2 = tp + a - 1;
        float4* dst = (float4*)&rowb[a][0];
        if ((unsigned)t2 < KL) {
            int pr = (t2 % KHS)*KHS + t2/KHS;
            const float4* src = (const float4*)&Yb[(size_t)pr*KL];
            for (int i = t; i < KL/4; i += 256) dst[i] = src[i];
        } else {
            float4 z = {0.f,0.f,0.f,0.f};
            for (int i = t; i < KL/4; i += 256) dst[i] = z;
        }
    }
    float w[9];
    #pragma unroll
    for (int i = 0; i < 9; i++) w[i] = fw[i];
    __syncthreads();
    const float* mmb = mm + bi*KL;
    float vals[9];
    float lmax = -1e30f;
    #pragma unroll
    for (int i = 0; i < 9; i++) {
        int q = t + i*256;
        int v = q / KHS, u = q - v*KHS;
        int tq = u*KHS + v;
        float acc = 0.f;
        #pragma unroll
        for (int b = 0; b < 3; b++) {
            int s2 = tq + b - 1;
            if ((unsigned)s2 >= KL) continue;
            int qr = (s2 % KHS)*KHS + s2/KHS;
            acc += w[b]*rowb[0][qr] + w[3 + b]*rowb[1][qr] + w[6 + b]*rowb[2][qr];
        }
        float val = acc * mmb[q] * 10.0f;
        vals[i] = val;
        lmax = fmaxf(lmax, val);
    }
    #pragma unroll
    for (int off = 32; off > 0; off >>= 1) lmax = fmaxf(lmax, __shfl_down(lmax, off));
    if ((t & 63) == 0) red[t >> 6] = lmax;
    __syncthreads();
    if (t == 0) {
        float m = red[0];
        for (int i = 1; i < 4; i++) m = fmaxf(m, red[i]);
        red[0] = m;
    }
    __syncthreads();
    float bmax = red[0];
    float lsum = 0.f;
    #pragma unroll
    for (int i = 0; i < 9; i++) {
        float e = __expf(vals[i] - bmax);
        vals[i] = e;
        lsum += e;
    }
    #pragma unroll
    for (int off = 32; off > 0; off >>= 1) lsum += __shfl_down(lsum, off);
    if ((t & 63) == 0) red[8 + (t >> 6)] = lsum;
    __syncthreads();
    if (t == 0) {
        float s = red[8];
        for (int i = 1; i < 4; i++) s += red[8 + i];
        red[8] = s;
    }
    __syncthreads();
    float inv = 1.0f / red[8];
    unsigned short* orow = Ybf + ((size_t)bi*KL + p)*KL;
    #pragma unroll
    for (int i = 0; i < 9; i++) {
        int q = t + i*256;
        orow[q] = f2bf(vals[i]*inv*mmb[q]);
    }
}

// ---------------- KR: Rt[n][k] bf16, n=(ky,kx,c), k=q -----------------------
__global__ __launch_bounds__(256) void k_buildRt(const float* __restrict__ bsrc,
    unsigned short* __restrict__ Rt)
{
    int idx = blockIdx.x*256 + threadIdx.x;   // nb*1024*288
    int k8 = idx % 288;
    int rest = idx / 288;
    int n  = rest % 1024;
    int bi = rest / 1024;
    int jj = n >> 6, c = n & 63;
    int ky = jj >> 2, kx = jj & 3;
    int k0 = k8*8;
    bf16x8 vv;
    #pragma unroll
    for (int j = 0; j < 8; j++) {
        int q = k0 + j;
        int v = q / KHS, u = q % KHS;
        int ry = 2*v + ky - 1, rx = 2*u + kx - 1;
        float val = 0.f;
        if ((unsigned)ry < KHH && (unsigned)rx < KHH)
            val = bsrc[(((size_t)bi*KHH + ry)*KHH + rx)*KC + c];
        vv[j] = (short)f2bf(val);
    }
    *(bf16x8*)&Rt[((size_t)bi*1024 + n)*KL + k0] = vv;
}

// ---------------- K8: overlap-add (adjoint of stride-2 4x4 SAME conv), /4 ---
__global__ __launch_bounds__(256) void k_overlap(const float* __restrict__ P,
    float* __restrict__ out)
{
    size_t gid = (size_t)blockIdx.x*256 + threadIdx.x;   // nb*96*96*64
    int c = gid & 63;
    size_t r = gid >> 6;
    int ix = (int)(r % KHH); r /= KHH;
    int iy = (int)(r % KHH);
    int bi = (int)(r / KHH);
    float acc = 0.f;
    #pragma unroll
    for (int sy = 0; sy < 2; sy++) {
        int ky = (iy & 1) ? (sy*2) : (sy*2 + 1);
        int yp = (iy + 1 - ky) >> 1;
        if ((unsigned)yp >= KHS) continue;
        #pragma unroll
        for (int sx = 0; sx < 2; sx++) {
            int kx = (ix & 1) ? (sx*2) : (sx*2 + 1);
            int xp = (ix + 1 - kx) >> 1;
            if ((unsigned)xp >= KHS) continue;
            acc += P[(((size_t)bi*KL + yp*KHS + xp)*16 + (ky*4 + kx))*64 + c];
        }
    }
    out[gid] = 0.25f * acc;
}

extern "C" void kernel_launch(void* const* d_in, const int* in_sizes, int n_in,
                              void* d_out, int out_size, void* d_ws, size_t ws_size,
                              hipStream_t stream)
{
    const float* f    = (const float*)d_in[0];
    const float* b    = (const float*)d_in[1];
    const float* mask = (const float*)d_in[2];
    const float* fw   = (const float*)d_in[3];
    float* out = (float*)d_out;

    auto need = [](int nbc) -> size_t {
        return (size_t)nbc * (2ull*KL*KC + 4ull*KL + 2ull*(size_t)KL*KL) * 4ull;
    };
    int nbc = 4;
    if (need(nbc) > ws_size) nbc = 2;
    if (need(nbc) > ws_size) nbc = 1;

    for (int bi0 = 0; bi0 < 4; bi0 += nbc) {
        int nb = (4 - bi0 < nbc) ? (4 - bi0) : nbc;
        const float* fc = f    + (size_t)bi0*KHH*KHH*KC;
        const float* bc = b    + (size_t)bi0*KHH*KHH*KC;
        const float* mc = mask + (size_t)bi0*KHH*KHH;
        float* outc = out + (size_t)bi0*KHH*KHH*KC;

        float* w    = (float*)d_ws;
        float* fd   = w;  w += (size_t)nbc*KL*KC;
        float* bd   = w;  w += (size_t)nbc*KL*KC;
        float* nbuf = w;  w += (size_t)nbc*KL;
        float* mdd  = w;  w += (size_t)nbc*KL;
        float* rnrm = w;  w += (size_t)nbc*KL;
        float* mmb  = w;  w += (size_t)nbc*KL;
        float* bufA = w;  w += (size_t)nbc*KL*KL;
        float* bufB = w;
        // lifetimes:
        //  bufB: [Ahat|Bhat] (bf16, 21 MB) -> Y1 (fp32) -> P (fp32)
        //  bufA: T (fp32) -> [Ybf bf16 | Rt bf16]
        unsigned short* Ahat = (unsigned short*)bufB;
        unsigned short* Bhat = Ahat + (size_t)nbc*KL*576;
        float* Tbuf = bufA;
        float* Y1   = bufB;
        unsigned short* Ybf = (unsigned short*)bufA;
        unsigned short* Rtb = Ybf + (size_t)nbc*KL*KL;
        float* Pbuf = bufB;

        k_prep      <<<nb*KL, 64, 0, stream>>>(fc, bc, mc, fd, bd, nbuf, mdd);
        k_normmask  <<<(nb*KL)/256, 256, 0, stream>>>(nbuf, mdd, rnrm, mmb);
        k_build_hilo<<<nb*KL, 64, 0, stream>>>(fd, bd, Ahat, Bhat);
        // T = Ahat * Bhat^T  (K=576; x-diag taps + split-bf16 folded into K)
        k_mfma_bt<576><<<dim3(18, 18, nb), 256, 0, stream>>>(
            Ahat, Bhat, Tbuf, KL, (size_t)KL*576, (size_t)KL*576, (size_t)KL*KL);
        // y-diag 3-tap * rnrm + fuse1: T (bufA) -> Y1 (bufB)
        k_fuse_a2   <<<dim3(9, 288, nb), 256, 0, stream>>>(Tbuf, rnrm, fw, Y1);
        // fuse2 + softmax: Y1 (bufB) -> Ybf (bufA)
        k_fuse_b    <<<dim3(KL, nb), 256, 0, stream>>>(Y1, fw, mmb, Ybf);
        k_buildRt   <<<(nb*1024*288)/256, 256, 0, stream>>>(bc, Rtb);
        // P = Ybf * Rt^T (K=2304)
        k_mfma_bt<2304><<<dim3(8, 18, nb), 256, 0, stream>>>(
            Ybf, Rtb, Pbuf, 1024, (size_t)KL*KL, (size_t)1024*KL, (size_t)KL*1024);
        k_overlap   <<<nb*KL, 256, 0, stream>>>(Pbuf, outc);
    }
}